// Round 3
// baseline (330.718 us; speedup 1.0000x reference)
//
#include <hip/hip_runtime.h>
#include <cstdint>
#include <cstddef>

// CRF loss forward: out[b] = log_norm(b) - target_score(b)
// B=512, N=1024, K=64. One wave (64 lanes) per batch row.
//
// Lane j owns alpha_j in exp-domain: z_j = exp(alpha_j - M0 - S*ln2).
// Per step: z_new_j = (sum_i z_i * E_ij) * exp(emit_j) * 2^-s,
// E_ij = exp(trans[i][j]) held in 64 VGPRs (column j per lane).
//
// R3 key change: NO LDS in the loop at all. Cross-lane broadcast of z_i
// is done with v_readlane (compile-time lane index -> SGPR) feeding
// v_fmac_f32 with SGPR src0. The per-step critical path is a pure-VALU
// issue stream (~64 readlane + 64 fmac into 8 chains), no lgkmcnt/vmcnt
// waits. Global emit/y_true/trans-pair loads stay in 8-deep register
// prefetch rings (off critical path).

constexpr int Nn = 1024;
constexpr int Kk = 64;
constexpr int P  = 8;   // emit/yt prefetch depth (power of 2)

__device__ __forceinline__ float rdlane(float v, int lane) {
    return __builtin_bit_cast(float,
        __builtin_amdgcn_readlane(__builtin_bit_cast(int, v), lane));
}

__global__ __launch_bounds__(64, 1) void crf_fwd(
    const float* __restrict__ y_pred,   // [B,N,K]
    const float* __restrict__ trans,    // [K,K]
    const int*   __restrict__ y_true,   // [B,N]
    float* __restrict__ out)            // [B]
{
    const int b = blockIdx.x;
    const int j = threadIdx.x;  // 0..63

    const float LOG2E = 1.4426950408889634f;
    const float LN2   = 0.6931471805599453f;

    // E column j: e[i] = exp(trans[i][j])  (coalesced: stride K across i)
    float e[Kk];
#pragma unroll
    for (int i = 0; i < Kk; ++i) {
        e[i] = exp2f(trans[i * Kk + j] * LOG2E);
    }

    const float* yp  = y_pred + (size_t)b * Nn * Kk;
    const int*   ytb = y_true + (size_t)b * Nn;

    // ---- t = 0 ----
    float emit0 = yp[j];
    bool  m0 = (bool)__all(emit0 > -1000000.0f);
    float a0 = m0 ? emit0 : 0.0f;
    float M0 = __uint_as_float(__builtin_amdgcn_readfirstlane(__float_as_uint(a0)));
    float z  = exp2f((a0 - M0) * LOG2E);

    int   yt0  = ytb[0];
    float pacc = (m0 && j == yt0) ? emit0 : 0.0f;  // point-score accumulator
    float tacc = 0.0f;                              // trans-pair accumulator
    int   S    = 0;                                 // pow2 rescale accumulator
    bool  m_prev = m0;

    // prefetch rings: emit/yt for steps 1..P, slot = step & (P-1)
    float ering[P];
    int   yring[P];
#pragma unroll
    for (int p = 1; p <= P; ++p) {
        ering[p & (P - 1)] = yp[(size_t)p * Kk + j];
        yring[p & (P - 1)] = ytb[p];
    }
    // tv ring (depth 2): tv for step t = trans[yt[t-1]*K + yt[t]], slot = t & 1
    float tvr[2];
    tvr[1] = trans[yt0      * Kk + yring[1]];   // step 1
    tvr[0] = trans[yring[1] * Kk + yring[2]];   // step 2

    auto STEP = [&](int t, int slot, int tslot) {
        float emit = ering[slot];
        int   yt   = yring[slot];
        // issue prefetch for step t+P into the just-freed slot
        int tt = t + P;
        tt = (tt > Nn - 1) ? (Nn - 1) : tt;
        ering[slot] = yp[(size_t)tt * Kk + j];
        yring[slot] = ytb[tt];

        bool m = (bool)__all(emit > -1000000.0f);

        // lagged pow2 rescale: exponent of lane-0's current z (exact)
        uint32_t zb0 = __builtin_amdgcn_readfirstlane(__float_as_uint(z));
        int s = (int)((zb0 >> 23) & 0xFF) - 127;

        float pe  = exp2f(emit * LOG2E);      // off critical path (emit from ring)
        float tvv = tvr[tslot];
        // prefetch tv for step t+2 (same slot): trans[yt[t+1]][yt[t+2]]
        tvr[tslot] = trans[yring[(slot + 1) & (P - 1)] * Kk +
                           yring[(slot + 2) & (P - 1)]];

        // dot_j = sum_i z_i * E_ij via readlane broadcast (no LDS!)
        // 8 independent accumulator chains of 8 fmac each.
        float zz = z;
        float a0c = 0.f, a1c = 0.f, a2c = 0.f, a3c = 0.f;
        float a4c = 0.f, a5c = 0.f, a6c = 0.f, a7c = 0.f;
#pragma unroll
        for (int i = 0; i < Kk; i += 8) {
            a0c = fmaf(rdlane(zz, i + 0), e[i + 0], a0c);
            a1c = fmaf(rdlane(zz, i + 1), e[i + 1], a1c);
            a2c = fmaf(rdlane(zz, i + 2), e[i + 2], a2c);
            a3c = fmaf(rdlane(zz, i + 3), e[i + 3], a3c);
            a4c = fmaf(rdlane(zz, i + 4), e[i + 4], a4c);
            a5c = fmaf(rdlane(zz, i + 5), e[i + 5], a5c);
            a6c = fmaf(rdlane(zz, i + 6), e[i + 6], a6c);
            a7c = fmaf(rdlane(zz, i + 7), e[i + 7], a7c);
        }
        float dot = ((a0c + a1c) + (a2c + a3c)) + ((a4c + a5c) + (a6c + a7c));

        float znew = __builtin_amdgcn_ldexpf(dot * pe, -s);
        z     = m ? znew : z;
        S    += m ? s : 0;
        pacc += (m && j == yt) ? emit : 0.0f;
        tacc += (m && m_prev) ? tvv : 0.0f;
        m_prev = m;
    };

    // main loop: 127 blocks of 8 (t = 1..1016), static ring indices
    for (int tb = 0; tb < 127; ++tb) {
        const int tbase = tb * 8;
#pragma unroll
        for (int u = 1; u <= 8; ++u) {
            STEP(tbase + u, u & 7, u & 1);
        }
    }
    // tail: t = 1017..1023 (fully unrolled, static indices)
#pragma unroll
    for (int t = 1017; t < Nn; ++t) {
        STEP(t, t & 7, t & 1);
    }

    // epilogue: wave reductions
    float sz = z;
    float sp = pacc;
#pragma unroll
    for (int off = 32; off; off >>= 1) {
        sz += __shfl_xor(sz, off);
        sp += __shfl_xor(sp, off);
    }

    if (j == 0) {
        float log_norm = logf(sz) + (float)S * LN2 + M0;
        out[b] = log_norm - (sp + tacc);
    }
}

extern "C" void kernel_launch(void* const* d_in, const int* in_sizes, int n_in,
                              void* d_out, int out_size, void* d_ws, size_t ws_size,
                              hipStream_t stream) {
    const float* y_pred = (const float*)d_in[0];
    const float* trans  = (const float*)d_in[1];
    const int*   y_true = (const int*)d_in[2];
    float* out = (float*)d_out;

    const int B = 512;
    crf_fwd<<<B, Kk, 0, stream>>>(y_pred, trans, y_true, out);
}

// Round 5
// 279.258 us; speedup vs baseline: 1.1843x; 1.1843x over previous
//
#include <hip/hip_runtime.h>
#include <cstdint>
#include <cstddef>

// CRF loss forward: out[b] = log_norm(b) - target_score(b)
// B=512, N=1024, K=64. One wave (64 lanes) per batch row.
//
// Lane j owns alpha_j in exp-domain: z_j = exp(alpha_j - M0 - S*ln2).
// Per step: z_new_j = (sum_i zs_i * E_ij) * exp(emit_j),  zs = ldexp(z,-s)
// (exact pow2 rescale applied BEFORE the dot so f16 conversion can't
// overflow; s = exponent of lane-0's z).
//
// R5 = R4 with the cvt_pkrtz type mismatch fixed via bit_cast
// (__builtin_amdgcn_cvt_pkrtz returns a __fp16 vector, not _Float16).
//  - E held as 32 f16x2 VGPRs.
//  - Broadcast halved: z normalized, packed to f16x2 via DPP lane^1 +
//    v_cvt_pkrtz, then 32 v_readlane (even lanes) -> 32 SGPRs, each
//    feeding v_dot2_f32_f16 (2 MACs/instr, f32 accum), 8 chains.
//  - Zero LDS / zero memory ops on the critical path; global loads stay
//    in 8-deep register prefetch rings.

constexpr int Nn = 1024;
constexpr int Kk = 64;
constexpr int P  = 8;   // emit/yt prefetch depth (power of 2)

typedef _Float16 v2h __attribute__((ext_vector_type(2)));

__device__ __forceinline__ v2h pk_f16(float lo, float hi) {
    return __builtin_bit_cast(v2h, __builtin_amdgcn_cvt_pkrtz(lo, hi));
}

__device__ __forceinline__ int lane_xor1(int v) {
#if __has_builtin(__builtin_amdgcn_mov_dpp)
    // quad_perm [1,0,3,2] = lane ^ 1, pure DPP (no LDS, no lgkmcnt)
    return __builtin_amdgcn_mov_dpp(v, 0xB1, 0xF, 0xF, true);
#else
    return __shfl_xor(v, 1);
#endif
}

#if __has_builtin(__builtin_amdgcn_fdot2)
#define DOT2(a, b, c) __builtin_amdgcn_fdot2((a), (b), (c), false)
#else
__device__ __forceinline__ float DOT2(v2h a, v2h b, float c) {
    return c + (float)a.x * (float)b.x + (float)a.y * (float)b.y;
}
#endif

__global__ __launch_bounds__(64, 1) void crf_fwd(
    const float* __restrict__ y_pred,   // [B,N,K]
    const float* __restrict__ trans,    // [K,K]
    const int*   __restrict__ y_true,   // [B,N]
    float* __restrict__ out)            // [B]
{
    const int b = blockIdx.x;
    const int j = threadIdx.x;  // 0..63

    const float LOG2E = 1.4426950408889634f;
    const float LN2   = 0.6931471805599453f;

    // E column j as f16 pairs: e2h[p] = {exp(T[2p][j]), exp(T[2p+1][j])}
    v2h e2h[Kk / 2];
#pragma unroll
    for (int p = 0; p < Kk / 2; ++p) {
        float lo = exp2f(trans[(2 * p)     * Kk + j] * LOG2E);
        float hi = exp2f(trans[(2 * p + 1) * Kk + j] * LOG2E);
        e2h[p] = pk_f16(lo, hi);
    }

    const float* yp  = y_pred + (size_t)b * Nn * Kk;
    const int*   ytb = y_true + (size_t)b * Nn;

    // ---- t = 0 ----
    float emit0 = yp[j];
    bool  m0 = (bool)__all(emit0 > -1000000.0f);
    float a0 = m0 ? emit0 : 0.0f;
    float M0 = __uint_as_float(__builtin_amdgcn_readfirstlane(__float_as_uint(a0)));
    float z  = exp2f((a0 - M0) * LOG2E);

    int   yt0  = ytb[0];
    float pacc = (m0 && j == yt0) ? emit0 : 0.0f;  // point-score accumulator
    float tacc = 0.0f;                              // trans-pair accumulator
    int   S    = 0;                                 // pow2 rescale accumulator
    bool  m_prev = m0;

    // prefetch rings: emit/yt for steps 1..P, slot = step & (P-1)
    float ering[P];
    int   yring[P];
#pragma unroll
    for (int p = 1; p <= P; ++p) {
        ering[p & (P - 1)] = yp[(size_t)p * Kk + j];
        yring[p & (P - 1)] = ytb[p];
    }
    // tv ring (depth 2): tv for step t = trans[yt[t-1]*K + yt[t]], slot = t & 1
    float tvr[2];
    tvr[1] = trans[yt0      * Kk + yring[1]];   // step 1
    tvr[0] = trans[yring[1] * Kk + yring[2]];   // step 2

    auto STEP = [&](int t, int slot, int tslot) {
        float emit = ering[slot];
        int   yt   = yring[slot];
        // issue prefetch for step t+P into the just-freed slot
        int tt = t + P;
        tt = (tt > Nn - 1) ? (Nn - 1) : tt;
        ering[slot] = yp[(size_t)tt * Kk + j];
        yring[slot] = ytb[tt];

        bool m = (bool)__all(emit > -1000000.0f);

        // exponent of lane-0's z (uniform across lanes)
        uint32_t zb0 = __builtin_amdgcn_readfirstlane(__float_as_uint(z));
        int s = (int)((zb0 >> 23) & 0xFF) - 127;

        float pe  = exp2f(emit * LOG2E);   // off critical path (emit from ring)
        float tvv = tvr[tslot];
        // prefetch tv for step t+2 (same slot): trans[yt[t+1]][yt[t+2]]
        tvr[tslot] = trans[yring[(slot + 1) & (P - 1)] * Kk +
                           yring[(slot + 2) & (P - 1)]];

        // normalize (exact pow2) BEFORE f16 conversion: zs in safe f16 range
        float zs = ldexpf(z, -s);
        int   zsb = __builtin_bit_cast(int, zs);
        int   znb = lane_xor1(zsb);
        float zn  = __builtin_bit_cast(float, znb);
        // even lane 2k now packs {zs_2k, zs_2k+1}
        v2h zp = pk_f16(zs, zn);
        int zi = __builtin_bit_cast(int, zp);

        // dot_j = sum_i zs_i * E_ij : 32 readlane (even lanes) + 32 dot2,
        // 8 independent f32 accumulator chains.
        float A0 = 0.f, A1 = 0.f, A2 = 0.f, A3 = 0.f;
        float A4 = 0.f, A5 = 0.f, A6 = 0.f, A7 = 0.f;
#define DS(k, A) { int sk = __builtin_amdgcn_readlane(zi, 2 * (k));            \
                   v2h hv = __builtin_bit_cast(v2h, sk);                       \
                   A = DOT2(hv, e2h[k], A); }
        DS(0, A0)  DS(1, A1)  DS(2, A2)  DS(3, A3)
        DS(4, A4)  DS(5, A5)  DS(6, A6)  DS(7, A7)
        DS(8, A0)  DS(9, A1)  DS(10, A2) DS(11, A3)
        DS(12, A4) DS(13, A5) DS(14, A6) DS(15, A7)
        DS(16, A0) DS(17, A1) DS(18, A2) DS(19, A3)
        DS(20, A4) DS(21, A5) DS(22, A6) DS(23, A7)
        DS(24, A0) DS(25, A1) DS(26, A2) DS(27, A3)
        DS(28, A4) DS(29, A5) DS(30, A6) DS(31, A7)
#undef DS
        float dot = ((A0 + A1) + (A2 + A3)) + ((A4 + A5) + (A6 + A7));

        float znew = dot * pe;   // s already consumed pre-dot (exact)
        z     = m ? znew : z;
        S    += m ? s : 0;
        pacc += (m && j == yt) ? emit : 0.0f;
        tacc += (m && m_prev) ? tvv : 0.0f;
        m_prev = m;
    };

    // main loop: 127 blocks of 8 (t = 1..1016), static ring indices
    for (int tb = 0; tb < 127; ++tb) {
        const int tbase = tb * 8;
#pragma unroll
        for (int u = 1; u <= 8; ++u) {
            STEP(tbase + u, u & 7, u & 1);
        }
    }
    // tail: t = 1017..1023 (fully unrolled, static indices)
#pragma unroll
    for (int t = 1017; t < Nn; ++t) {
        STEP(t, t & 7, t & 1);
    }

    // epilogue: wave reductions
    float sz = z;
    float sp = pacc;
#pragma unroll
    for (int off = 32; off; off >>= 1) {
        sz += __shfl_xor(sz, off);
        sp += __shfl_xor(sp, off);
    }

    if (j == 0) {
        float log_norm = logf(sz) + (float)S * LN2 + M0;
        out[b] = log_norm - (sp + tacc);
    }
}

extern "C" void kernel_launch(void* const* d_in, const int* in_sizes, int n_in,
                              void* d_out, int out_size, void* d_ws, size_t ws_size,
                              hipStream_t stream) {
    const float* y_pred = (const float*)d_in[0];
    const float* trans  = (const float*)d_in[1];
    const int*   y_true = (const int*)d_in[2];
    float* out = (float*)d_out;

    const int B = 512;
    crf_fwd<<<B, Kk, 0, stream>>>(y_pred, trans, y_true, out);
}

// Round 6
// 278.747 us; speedup vs baseline: 1.1864x; 1.0018x over previous
//
#include <hip/hip_runtime.h>
#include <cstdint>
#include <cstddef>

// CRF loss forward: out[b] = log_norm(b) - target_score(b)
// B=512, N=1024, K=64. One wave (64 lanes) per batch row.
//
// Lane j owns alpha_j in exp-domain: z_j = exp(alpha_j - M0 - S*ln2).
// Per step: z_new_j = (sum_i zs_i * E_ij) * exp(emit_j),  zs = ldexp(z,-s)
// (exact pow2 rescale applied BEFORE the f16 pack; s = exponent of
// lane-0's z).
//
// R6 vs R5: R5's VGPR_Count=40 proved e2h[32] was demoted to scratch
// (32 hidden L1 reads per step -> VALUBusy stuck at 28%). Fix: E held
// in 32 INDIVIDUALLY NAMED v2h locals (X-macro) + asm keep-alive, so
// the allocator cannot silently spill the array. E converted with RNE
// (not RTZ) to kill systematic per-step bias.
//  - Broadcast: z normalized, packed to f16x2 via DPP lane^1 + cvt_pkrtz,
//    32 v_readlane (even lanes) -> SGPRs feeding v_dot2_f32_f16, 8 chains.
//  - Zero LDS / zero memory ops on the critical path; global loads in
//    8-deep register prefetch rings.

constexpr int Nn = 1024;
constexpr int Kk = 64;
constexpr int P  = 8;   // emit/yt prefetch depth (power of 2)

typedef _Float16 v2h __attribute__((ext_vector_type(2)));

__device__ __forceinline__ v2h pk_f16_rtz(float lo, float hi) {
    return __builtin_bit_cast(v2h, __builtin_amdgcn_cvt_pkrtz(lo, hi));
}

__device__ __forceinline__ int lane_xor1(int v) {
    // quad_perm [1,0,3,2] = lane ^ 1, pure DPP (no LDS, no lgkmcnt)
    return __builtin_amdgcn_mov_dpp(v, 0xB1, 0xF, 0xF, true);
}

#if __has_builtin(__builtin_amdgcn_fdot2)
#define DOT2(a, b, c) __builtin_amdgcn_fdot2((a), (b), (c), false)
#else
__device__ __forceinline__ float DOT2(v2h a, v2h b, float c) {
    return c + (float)a.x * (float)b.x + (float)a.y * (float)b.y;
}
#endif

// X-macro over the 32 E-register names
#define E_LIST(X) X(0) X(1) X(2) X(3) X(4) X(5) X(6) X(7) \
                  X(8) X(9) X(10) X(11) X(12) X(13) X(14) X(15) \
                  X(16) X(17) X(18) X(19) X(20) X(21) X(22) X(23) \
                  X(24) X(25) X(26) X(27) X(28) X(29) X(30) X(31)

__global__ __launch_bounds__(64, 1) void crf_fwd(
    const float* __restrict__ y_pred,   // [B,N,K]
    const float* __restrict__ trans,    // [K,K]
    const int*   __restrict__ y_true,   // [B,N]
    float* __restrict__ out)            // [B]
{
    const int b = blockIdx.x;
    const int j = threadIdx.x;  // 0..63

    const float LOG2E = 1.4426950408889634f;
    const float LN2   = 0.6931471805599453f;

    // E column j as f16 pairs in NAMED registers:
    // e_k = {exp(T[2k][j]), exp(T[2k+1][j])}, RNE conversion.
#define E_DECL(k) v2h e_##k;
    E_LIST(E_DECL)
#undef E_DECL
#define E_INIT(k) { float lo_ = exp2f(trans[(2*(k))     * Kk + j] * LOG2E);   \
                    float hi_ = exp2f(trans[(2*(k) + 1) * Kk + j] * LOG2E);   \
                    e_##k = (v2h){(_Float16)lo_, (_Float16)hi_}; }
    E_LIST(E_INIT)
#undef E_INIT
    // keep-alive: pin all 32 E values into VGPRs (defeats scratch demotion)
    {
        float dummy_ = 0.0f;
#define E_KEEP(k) , "+v"(e_##k)
        asm volatile("" : "+v"(dummy_) E_LIST(E_KEEP));
#undef E_KEEP
    }

    const float* yp  = y_pred + (size_t)b * Nn * Kk;
    const int*   ytb = y_true + (size_t)b * Nn;

    // ---- t = 0 ----
    float emit0 = yp[j];
    bool  m0 = (bool)__all(emit0 > -1000000.0f);
    float a0 = m0 ? emit0 : 0.0f;
    float M0 = __uint_as_float(__builtin_amdgcn_readfirstlane(__float_as_uint(a0)));
    float z  = exp2f((a0 - M0) * LOG2E);

    int   yt0  = ytb[0];
    float pacc = (m0 && j == yt0) ? emit0 : 0.0f;  // point-score accumulator
    float tacc = 0.0f;                              // trans-pair accumulator
    int   S    = 0;                                 // pow2 rescale accumulator
    bool  m_prev = m0;

    // prefetch rings: emit/yt for steps 1..P, slot = step & (P-1)
    float ering[P];
    int   yring[P];
#pragma unroll
    for (int p = 1; p <= P; ++p) {
        ering[p & (P - 1)] = yp[(size_t)p * Kk + j];
        yring[p & (P - 1)] = ytb[p];
    }
    // tv ring (depth 2): tv for step t = trans[yt[t-1]*K + yt[t]], slot = t & 1
    float tvr[2];
    tvr[1] = trans[yt0      * Kk + yring[1]];   // step 1
    tvr[0] = trans[yring[1] * Kk + yring[2]];   // step 2

    auto STEP = [&](int t, int slot, int tslot) {
        float emit = ering[slot];
        int   yt   = yring[slot];
        // issue prefetch for step t+P into the just-freed slot
        int tt = t + P;
        tt = (tt > Nn - 1) ? (Nn - 1) : tt;
        ering[slot] = yp[(size_t)tt * Kk + j];
        yring[slot] = ytb[tt];

        bool m = (bool)__all(emit > -1000000.0f);

        // exponent of lane-0's z (uniform across lanes)
        uint32_t zb0 = __builtin_amdgcn_readfirstlane(__float_as_uint(z));
        int s = (int)((zb0 >> 23) & 0xFF) - 127;

        float pe  = exp2f(emit * LOG2E);   // off critical path (emit from ring)
        float tvv = tvr[tslot];
        // prefetch tv for step t+2 (same slot): trans[yt[t+1]][yt[t+2]]
        tvr[tslot] = trans[yring[(slot + 1) & (P - 1)] * Kk +
                           yring[(slot + 2) & (P - 1)]];

        // normalize (exact pow2) BEFORE f16 conversion: zs in safe f16 range
        float zs = ldexpf(z, -s);
        int   zsb = __builtin_bit_cast(int, zs);
        int   znb = lane_xor1(zsb);
        float zn  = __builtin_bit_cast(float, znb);
        // even lane 2k now packs {zs_2k, zs_2k+1}
        v2h zp = pk_f16_rtz(zs, zn);
        int zi = __builtin_bit_cast(int, zp);

        // dot_j = sum_i zs_i * E_ij : 32 readlane (even lanes) + 32 dot2,
        // 8 independent f32 accumulator chains.
        float A0 = 0.f, A1 = 0.f, A2 = 0.f, A3 = 0.f;
        float A4 = 0.f, A5 = 0.f, A6 = 0.f, A7 = 0.f;
#define DS(k, A) { int sk = __builtin_amdgcn_readlane(zi, 2 * (k));            \
                   v2h hv = __builtin_bit_cast(v2h, sk);                       \
                   A = DOT2(hv, e_##k, A); }
        DS(0, A0)  DS(1, A1)  DS(2, A2)  DS(3, A3)
        DS(4, A4)  DS(5, A5)  DS(6, A6)  DS(7, A7)
        DS(8, A0)  DS(9, A1)  DS(10, A2) DS(11, A3)
        DS(12, A4) DS(13, A5) DS(14, A6) DS(15, A7)
        DS(16, A0) DS(17, A1) DS(18, A2) DS(19, A3)
        DS(20, A4) DS(21, A5) DS(22, A6) DS(23, A7)
        DS(24, A0) DS(25, A1) DS(26, A2) DS(27, A3)
        DS(28, A4) DS(29, A5) DS(30, A6) DS(31, A7)
#undef DS
        float dot = ((A0 + A1) + (A2 + A3)) + ((A4 + A5) + (A6 + A7));

        float znew = dot * pe;   // s already consumed pre-dot (exact)
        z     = m ? znew : z;
        S    += m ? s : 0;
        pacc += (m && j == yt) ? emit : 0.0f;
        tacc += (m && m_prev) ? tvv : 0.0f;
        m_prev = m;
    };

    // main loop: 127 blocks of 8 (t = 1..1016), static ring indices
    for (int tb = 0; tb < 127; ++tb) {
        const int tbase = tb * 8;
#pragma unroll
        for (int u = 1; u <= 8; ++u) {
            STEP(tbase + u, u & 7, u & 1);
        }
    }
    // tail: t = 1017..1023 (fully unrolled, static indices)
#pragma unroll
    for (int t = 1017; t < Nn; ++t) {
        STEP(t, t & 7, t & 1);
    }

    // epilogue: wave reductions
    float sz = z;
    float sp = pacc;
#pragma unroll
    for (int off = 32; off; off >>= 1) {
        sz += __shfl_xor(sz, off);
        sp += __shfl_xor(sp, off);
    }

    if (j == 0) {
        float log_norm = logf(sz) + (float)S * LN2 + M0;
        out[b] = log_norm - (sp + tacc);
    }
}

extern "C" void kernel_launch(void* const* d_in, const int* in_sizes, int n_in,
                              void* d_out, int out_size, void* d_ws, size_t ws_size,
                              hipStream_t stream) {
    const float* y_pred = (const float*)d_in[0];
    const float* trans  = (const float*)d_in[1];
    const int*   y_true = (const int*)d_in[2];
    float* out = (float*)d_out;

    const int B = 512;
    crf_fwd<<<B, Kk, 0, stream>>>(y_pred, trans, y_true, out);
}